// Round 10
// baseline (1592.555 us; speedup 1.0000x reference)
//
#include <hip/hip_runtime.h>
#include <hip/hip_bf16.h>

#define LNUM 6
#define BB 16
#define TT 512
#define DD 512
#define HH 8
#define AA 64
#define FFD 2048
#define EE 200000
#define BIASDIM 4
#define ATT_NEG (-3.402823466e38f)

typedef __bf16 bf16_t;
typedef __attribute__((ext_vector_type(8))) __bf16 bf16x8;
typedef __attribute__((ext_vector_type(4))) float f32x4;

typedef __attribute__((address_space(3))) void lds_void;
typedef const __attribute__((address_space(1))) void glb_void;

__device__ __forceinline__ void async_load16(const bf16_t* g, bf16_t* l) {
    __builtin_amdgcn_global_load_lds((glb_void*)g, (lds_void*)l, 16, 0, 0);
}

// ---------------------------------------------------------------------------
// Embedding + positional encoding (fp32 out)
// ---------------------------------------------------------------------------
__global__ __launch_bounds__(256) void embed_pe_kernel(
    const int* __restrict__ tokens, const float* __restrict__ embed,
    float* __restrict__ x)
{
    int idx = blockIdx.x * 256 + threadIdx.x;
    int d  = idx & (DD - 1);
    int bt = idx >> 9;
    int t  = bt & (TT - 1);
    int tok = tokens[bt];
    float e = embed[(long long)tok * DD + d] * 22.62741699796952f; // sqrt(512)
    float p = (float)(2 * (d >> 1)) * (1.0f / (float)DD);
    float denom = exp2f(p * 13.287712379549449f);  // 10000^p
    float angle = (float)t / denom;
    float pe = (d & 1) ? cosf(angle) : sinf(angle);
    x[idx] = e + pe;
}

// ---------------------------------------------------------------------------
// LayerNorm over D=512, fp32 in, TO out
// ---------------------------------------------------------------------------
template <typename TO>
__global__ __launch_bounds__(256) void ln_kernel(
    const float* __restrict__ x, TO* __restrict__ y,
    const float* __restrict__ g, const float* __restrict__ b)
{
    long long row = blockIdx.x;
    const float* xr = x + row * DD;
    int tid = threadIdx.x;
    float v0 = xr[tid], v1 = xr[tid + 256];
    float s = v0 + v1, sq = v0 * v0 + v1 * v1;
#pragma unroll
    for (int o = 32; o > 0; o >>= 1) {
        s  += __shfl_down(s, o);
        sq += __shfl_down(sq, o);
    }
    __shared__ float ss[4], sq4[4];
    if ((tid & 63) == 0) { ss[tid >> 6] = s; sq4[tid >> 6] = sq; }
    __syncthreads();
    float st  = ss[0] + ss[1] + ss[2] + ss[3];
    float sqt = sq4[0] + sq4[1] + sq4[2] + sq4[3];
    float mean = st * (1.0f / DD);
    float var  = sqt * (1.0f / DD) - mean * mean;
    float inv  = rsqrtf(var + 1e-3f);
    y[row * DD + tid]       = (TO)((v0 - mean) * inv * g[tid]       + b[tid]);
    y[row * DD + tid + 256] = (TO)((v1 - mean) * inv * g[tid + 256] + b[tid + 256]);
}

// ---------------------------------------------------------------------------
// Fused split-K partial reduce + residual update + LayerNorm.
// v = x + sum_s P[s];  x = v (residual write-back);  y = LN(v)
// ---------------------------------------------------------------------------
template <typename TO, int S>
__global__ __launch_bounds__(256) void reduce_ln_kernel(
    float* __restrict__ x, const float* __restrict__ P,
    TO* __restrict__ y, const float* __restrict__ g, const float* __restrict__ b)
{
    const long long NXc = (long long)BB * TT * DD;
    long long row = blockIdx.x;
    int tid = threadIdx.x;
    long long i0 = row * DD + tid;
    float v0 = x[i0], v1 = x[i0 + 256];
#pragma unroll
    for (int s = 0; s < S; s++) {
        v0 += P[(long long)s * NXc + i0];
        v1 += P[(long long)s * NXc + i0 + 256];
    }
    x[i0] = v0; x[i0 + 256] = v1;
    float s2 = v0 + v1, sq = v0 * v0 + v1 * v1;
#pragma unroll
    for (int o = 32; o > 0; o >>= 1) {
        s2 += __shfl_down(s2, o);
        sq += __shfl_down(sq, o);
    }
    __shared__ float ss[4], sq4[4];
    if ((tid & 63) == 0) { ss[tid >> 6] = s2; sq4[tid >> 6] = sq; }
    __syncthreads();
    float st  = ss[0] + ss[1] + ss[2] + ss[3];
    float sqt = sq4[0] + sq4[1] + sq4[2] + sq4[3];
    float mean = st * (1.0f / DD);
    float var  = sqt * (1.0f / DD) - mean * mean;
    float inv  = rsqrtf(var + 1e-3f);
    y[i0]       = (TO)((v0 - mean) * inv * g[tid]       + b[tid]);
    y[i0 + 256] = (TO)((v1 - mean) * inv * g[tid + 256] + b[tid + 256]);
}

// ---------------------------------------------------------------------------
// ksum[b,t,h] = sum_a k_bf[b,t,h,a]
// ---------------------------------------------------------------------------
__global__ __launch_bounds__(256) void ksum_kernel(
    const bf16_t* __restrict__ k, float* __restrict__ ks)
{
    int idx = blockIdx.x * 256 + threadIdx.x;
    long long base = (long long)idx * AA;
    float s = 0.f;
#pragma unroll
    for (int a = 0; a < AA; a++) s += (float)k[base + a];
    ks[idx] = s;
}

// ---------------------------------------------------------------------------
// ONE-TIME edge-count scatter: cm[b,q,k] += 1 << (4*type). Counts are
// layer-independent (edge indices fixed); per-layer dense = sum_t ev_l[t]*cnt.
// Nibble overflow needs >=16 same-type edges on one (b,q,k): P ~ 1e-40.
// ---------------------------------------------------------------------------
__global__ __launch_bounds__(256) void cnt_scatter_kernel(
    const int* __restrict__ ab, unsigned int* __restrict__ cm)
{
    int e = blockIdx.x * 256 + threadIdx.x;
    if (e < EE) {
        int ty = ab[e * 4 + 0];
        int b  = ab[e * 4 + 1];
        int q  = ab[e * 4 + 2];
        int kk = ab[e * 4 + 3];
        atomicAdd(&cm[((long long)b * TT + q) * TT + kk], 1u << (4 * ty));
    }
}

// ONE-TIME: fold bf16(mask) into the hi16 of cm. {bf16(mask) | 4x4-bit cnt}
__global__ __launch_bounds__(256) void cm_mask_kernel(
    unsigned int* __restrict__ cm, const float* __restrict__ masks)
{
    long long i = ((long long)blockIdx.x * 256 + threadIdx.x) * 4;
    uint4 c = *(const uint4*)(cm + i);
    f32x4 m = *(const f32x4*)(masks + i);
    c.x = (__float_as_uint(m[0]) & 0xffff0000u) | (c.x & 0xffffu);
    c.y = (__float_as_uint(m[1]) & 0xffff0000u) | (c.y & 0xffffu);
    c.z = (__float_as_uint(m[2]) & 0xffff0000u) | (c.z & 0xffffu);
    c.w = (__float_as_uint(m[3]) & 0xffff0000u) | (c.w & 0xffffu);
    *(uint4*)(cm + i) = c;
}

// ---------------------------------------------------------------------------
// Weight convert+transpose: in fp32 [R,Cc] -> out bf16 [Cc,R]. 64x64 tiles.
// ---------------------------------------------------------------------------
__global__ __launch_bounds__(256) void wconv_kernel(
    const float* __restrict__ in, bf16_t* __restrict__ out, int R, int Cc)
{
    __shared__ bf16_t tile[64][65];
    int c0 = blockIdx.x * 64, r0 = blockIdx.y * 64;
    int tid = threadIdx.x;
#pragma unroll
    for (int i = 0; i < 16; i++) {
        int idx = tid + i * 256; int r = idx >> 6, c = idx & 63;
        tile[c][r] = (bf16_t)in[(long long)(r0 + r) * Cc + c0 + c];
    }
    __syncthreads();
#pragma unroll
    for (int i = 0; i < 16; i++) {
        int idx = tid + i * 256; int rr = idx >> 6, cc = idx & 63;
        out[(long long)(c0 + rr) * R + r0 + cc] = tile[rr][cc];
    }
}

struct Ptr4 { const float* p[4]; };

__global__ __launch_bounds__(256) void wconv4_kernel(Ptr4 srcs, bf16_t* __restrict__ out)
{
    __shared__ bf16_t tile[64][65];
    int z = blockIdx.z;
    const float* in = srcs.p[z];
    bf16_t* o = out + (long long)z * DD * DD;
    int c0 = blockIdx.x * 64, r0 = blockIdx.y * 64;
    int tid = threadIdx.x;
#pragma unroll
    for (int i = 0; i < 16; i++) {
        int idx = tid + i * 256; int r = idx >> 6, c = idx & 63;
        tile[c][r] = (bf16_t)in[(long long)(r0 + r) * DD + c0 + c];
    }
    __syncthreads();
#pragma unroll
    for (int i = 0; i < 16; i++) {
        int idx = tid + i * 256; int rr = idx >> 6, cc = idx & 63;
        o[(long long)(c0 + rr) * DD + r0 + cc] = tile[rr][cc];
    }
}

// ---------------------------------------------------------------------------
// v [B,T,H,A] bf16 -> vT [B,H,A,T] bf16
// ---------------------------------------------------------------------------
__global__ __launch_bounds__(256) void vtrans_kernel(
    const bf16_t* __restrict__ v, bf16_t* __restrict__ vT)
{
    __shared__ bf16_t tile[64][65];
    int bh = blockIdx.y; int b = bh >> 3, h = bh & 7;
    int t0 = blockIdx.x * 64;
    int tid = threadIdx.x;
#pragma unroll
    for (int i = 0; i < 16; i++) {
        int idx = tid + i * 256; int r = idx >> 6, c = idx & 63;  // r: t, c: a
        tile[c][r] = v[((long long)(b * TT + t0 + r) * HH + h) * AA + c];
    }
    __syncthreads();
#pragma unroll
    for (int i = 0; i < 16; i++) {
        int idx = tid + i * 256; int a = idx >> 6, t2 = idx & 63;
        vT[(((long long)b * HH + h) * AA + a) * TT + t0 + t2] = tile[a][t2];
    }
}

// ---------------------------------------------------------------------------
// Fused attention, R10: R9 + DOUBLE-BUFFERED K/V staging (ping-pong, R1
// discipline — no manual vmcnt, so no interaction with compiler cm loads):
//   for kt:  prefetch cm/ksum(kt) -> VGPRs       (drains at next barrier)
//            __syncthreads()                      (buf[cur^1] readers done;
//                                                 vmcnt0: stage_kt + cm done)
//            if kt+1<8: stage(kt+1 -> buf[cur^1]) (covered by tile compute)
//            QK(buf[cur]) -> decode -> softmax -> PV(buf[cur])
// One barrier/tile (was 2); the ~900-cyc staging latency is covered by the
// ~1000-cyc tile compute instead of being fully exposed at the barrier.
// LDS: 2x8K K + 2x8K V + 11K P = 43.3 KB -> 3 blocks/CU (>= measured 2.4).
// ---------------------------------------------------------------------------
__global__ __launch_bounds__(256) void fused_attn_kernel(
    const bf16_t* __restrict__ qg, const bf16_t* __restrict__ kg,
    const bf16_t* __restrict__ vT, const unsigned int* __restrict__ cm,
    const float* __restrict__ ksum, const float* __restrict__ be_l,
    const float* __restrict__ bs_l, bf16_t* __restrict__ ctx)
{
    __shared__ __align__(16) bf16_t Ks[2][64 * 64];
    __shared__ __align__(16) bf16_t Vs[2][64 * 64];
    __shared__ __align__(16) bf16_t Plds[4 * 16 * 88];
    __shared__ float evs[BIASDIM];

    int tid = threadIdx.x;
    int wave = tid >> 6, lane = tid & 63;
    int row16 = lane & 15, quad = lane >> 4;
    int bid = blockIdx.x;
    int bh = bid & 127; int b = bh >> 3, h = bh & 7;
    int qw = (bid >> 7) * 64 + wave * 16;

    // ev[t] = sum_a be[t][a]*bs[a]  (wave 0; visible after first barrier)
    if (wave == 0) {
        float bsv = bs_l[lane];
#pragma unroll
        for (int t = 0; t < BIASDIM; t++) {
            float p = be_l[t * AA + lane] * bsv;
#pragma unroll
            for (int off = 32; off > 0; off >>= 1) p += __shfl_xor(p, off);
            if (lane == 0) evs[t] = p;
        }
    }

    bf16x8 qf[2];
    {
        const bf16_t* qp = qg + (((long long)b * TT + qw + row16) * HH + h) * AA + quad * 8;
        qf[0] = *(const bf16x8*)(qp);
        qf[1] = *(const bf16x8*)(qp + 32);
    }

    f32x4 o[4] = {};
    float m_r[4], l_r[4];
#pragma unroll
    for (int r = 0; r < 4; r++) { m_r[r] = -3.0e38f; l_r[r] = 0.f; }

    bf16_t* Pw = Plds + wave * 16 * 88;
    const unsigned int* cmbase = cm + (long long)b * TT * TT;
    const float* ksbase = ksum + (long long)b * TT * HH + h;

    // stage helper (lambda-free macro-ish): stage k-tile tt into buffer sl
#define ASTAGE(tt, sl)                                                        \
    {                                                                         \
        int tbase = (tt) * 64;                                                \
        _Pragma("unroll")                                                     \
        for (int p = tid; p < 512; p += 256) {                                \
            int r = p >> 3, s = p & 7, c = s ^ (r & 7);                       \
            async_load16(kg + (((long long)b * TT + tbase + r) * HH + h) * AA \
                             + c * 8, Ks[sl] + p * 8);                        \
        }                                                                     \
        _Pragma("unroll")                                                     \
        for (int p = tid; p < 512; p += 256) {                                \
            int r = p >> 3, s = p & 7, c = s ^ (r & 7);                       \
            async_load16(vT + ((long long)bh * AA + r) * TT + tbase + c * 8,  \
                         Vs[sl] + p * 8);                                     \
        }                                                                     \
    }

    ASTAGE(0, 0);

    for (int kt = 0; kt < 8; kt++) {
        int cur = kt & 1;
        int t0 = kt * 64;

        // prefetch packed cm + ksum for this tile (drained by the barrier)
        unsigned int cmw[4][4];
        float ksv4[4];
#pragma unroll
        for (int n = 0; n < 4; n++) {
            int ktok = t0 + n * 16 + row16;
            ksv4[n] = ksbase[(long long)ktok * HH];
#pragma unroll
            for (int r = 0; r < 4; r++)
                cmw[n][r] = cmbase[(long long)(qw + quad * 4 + r) * TT + ktok];
        }

        __syncthreads();   // stage_kt + cm_kt complete; buf[cur^1] free

        if (kt + 1 < 8) ASTAGE(kt + 1, cur ^ 1);

        f32x4 s4[4] = {};
        __builtin_amdgcn_s_setprio(1);
#pragma unroll
        for (int n = 0; n < 4; n++) {
            int row = n * 16 + row16;
            int sw = row & 7;
            bf16x8 kf0 = *(const bf16x8*)(Ks[cur] + row * 64 + ((quad ^ sw) * 8));
            bf16x8 kf1 = *(const bf16x8*)(Ks[cur] + row * 64 + (((quad + 4) ^ sw) * 8));
            s4[n] = __builtin_amdgcn_mfma_f32_16x16x32_bf16(qf[0], kf0, s4[n], 0, 0, 0);
            s4[n] = __builtin_amdgcn_mfma_f32_16x16x32_bf16(qf[1], kf1, s4[n], 0, 0, 0);
        }
        __builtin_amdgcn_s_setprio(0);

        float e0 = evs[0], e1 = evs[1], e2 = evs[2], e3 = evs[3];
        float val[4][4];
#pragma unroll
        for (int n = 0; n < 4; n++) {
#pragma unroll
            for (int r = 0; r < 4; r++) {
                unsigned int w = cmw[n][r];
                float mk = __uint_as_float(w & 0xffff0000u);
                float d = e0 * (float)(w & 15u)
                        + e1 * (float)((w >> 4) & 15u)
                        + e2 * (float)((w >> 8) & 15u)
                        + e3 * (float)((w >> 12) & 15u);
                float vv = 0.125f * fmaf(d, ksv4[n], s4[n][r]);
                val[n][r] = (mk == 0.f) ? ATT_NEG : vv * mk;
            }
        }

        float scl[4];
#pragma unroll
        for (int r = 0; r < 4; r++) {
            float mx = fmaxf(fmaxf(val[0][r], val[1][r]), fmaxf(val[2][r], val[3][r]));
#pragma unroll
            for (int off = 1; off < 16; off <<= 1) mx = fmaxf(mx, __shfl_xor(mx, off));
            float mnew = fmaxf(m_r[r], mx);
            float sc = __expf(m_r[r] - mnew);
            float ps = 0.f;
#pragma unroll
            for (int n = 0; n < 4; n++) {
                float p = __expf(val[n][r] - mnew);
                val[n][r] = p;
                ps += p;
            }
#pragma unroll
            for (int off = 1; off < 16; off <<= 1) ps += __shfl_xor(ps, off);
            l_r[r] = l_r[r] * sc + ps;
            m_r[r] = mnew;
            scl[r] = sc;
        }
#pragma unroll
        for (int j = 0; j < 4; j++)
#pragma unroll
            for (int r = 0; r < 4; r++) o[j][r] *= scl[r];

#pragma unroll
        for (int n = 0; n < 4; n++)
#pragma unroll
            for (int r = 0; r < 4; r++)
                Pw[(quad * 4 + r) * 88 + n * 16 + row16] = (bf16_t)val[n][r];
        asm volatile("s_waitcnt lgkmcnt(0)" ::: "memory");

        bf16x8 pa0 = *(const bf16x8*)(Pw + row16 * 88 + quad * 8);
        bf16x8 pa1 = *(const bf16x8*)(Pw + row16 * 88 + 32 + quad * 8);
        __builtin_amdgcn_s_setprio(1);
#pragma unroll
        for (int j = 0; j < 4; j++) {
            int row = j * 16 + row16;
            int sw = row & 7;
            bf16x8 vb0 = *(const bf16x8*)(Vs[cur] + row * 64 + ((quad ^ sw) * 8));
            bf16x8 vb1 = *(const bf16x8*)(Vs[cur] + row * 64 + (((quad + 4) ^ sw) * 8));
            o[j] = __builtin_amdgcn_mfma_f32_16x16x32_bf16(pa0, vb0, o[j], 0, 0, 0);
            o[j] = __builtin_amdgcn_mfma_f32_16x16x32_bf16(pa1, vb1, o[j], 0, 0, 0);
        }
        __builtin_amdgcn_s_setprio(0);
    }
#undef ASTAGE

#pragma unroll
    for (int r = 0; r < 4; r++) {
        float invl = 1.0f / l_r[r];
        int qgl = qw + quad * 4 + r;
        bf16_t* cp = ctx + (((long long)b * TT + qgl) * HH + h) * AA;
#pragma unroll
        for (int j = 0; j < 4; j++)
            cp[j * 16 + row16] = (bf16_t)(o[j][r] * invl);
    }
}

// ===========================================================================
// gemm_pipe (exact R4 version — verified best): 128x128 tile, BK=64, 4
// waves, 64 KB double-buffered LDS, counted-vmcnt pipeline. See R4 comments.
// ===========================================================================
#define PSTAGE(kc0, slot)                                                     \
    {                                                                         \
        bf16_t* At = sm + (slot) * 16384;                                     \
        bf16_t* Bt = At + 8192;                                               \
        _Pragma("unroll")                                                     \
        for (int i = 0; i < 4; i++) {                                         \
            int qq = tid + i * 256;                                           \
            int r = qq >> 3, ck = qq & 7;                                     \
            int cc = (kc0) + ((ck ^ (r & 7)) * 8);                            \
            async_load16(Ag + (long long)(m0 + r) * lda + cc, At + qq * 8);   \
            async_load16(Bg + (long long)(n0 + r) * ldb + cc, Bt + qq * 8);   \
        }                                                                     \
    }

#define PLOAD()                                                               \
    _Pragma("unroll")                                                         \
    for (int mf = 0; mf < 4; mf++) {                                          \
        int ra = wm * 64 + mf * 16 + row16;                                   \
        _Pragma("unroll")                                                     \
        for (int ks2 = 0; ks2 < 2; ks2++)                                     \
            a8[mf][ks2] = *(const bf16x8*)(Ac + ra * 64 +                     \
                              (((ks2 * 4 + quad) ^ (ra & 7)) * 8));           \
    }                                                                         \
    _Pragma("unroll")                                                         \
    for (int nf = 0; nf < 4; nf++) {                                          \
        int rb = wn * 64 + nf * 16 + row16;                                   \
        _Pragma("unroll")                                                     \
        for (int ks2 = 0; ks2 < 2; ks2++)                                     \
            b8[nf][ks2] = *(const bf16x8*)(Bc + rb * 64 +                     \
                              (((ks2 * 4 + quad) ^ (rb & 7)) * 8));           \
    }

#define PMM()                                                                 \
    _Pragma("unroll")                                                         \
    for (int mf = 0; mf < 4; mf++)                                            \
        _Pragma("unroll")                                                     \
        for (int nf = 0; nf < 4; nf++)                                        \
            _Pragma("unroll")                                                 \
            for (int ks2 = 0; ks2 < 2; ks2++)                                 \
                acc[mf][nf] = __builtin_amdgcn_mfma_f32_16x16x32_bf16(        \
                    a8[mf][ks2], b8[nf][ks2], acc[mf][nf], 0, 0, 0);

#define PIPE_BODY(KBEG, NT)                                                   \
    PSTAGE((KBEG), 0);                                                        \
    int c = 0;                                                                \
    for (int t = 0; t < (NT); ++t, c ^= 1) {                                  \
        if (t + 1 < (NT)) {                                                   \
            PSTAGE((KBEG) + (t + 1) * 64, c ^ 1);                             \
            asm volatile("s_waitcnt vmcnt(8)" ::: "memory");                  \
        } else {                                                              \
            asm volatile("s_waitcnt vmcnt(0)" ::: "memory");                  \
        }                                                                     \
        __builtin_amdgcn_sched_barrier(0);                                    \
        __builtin_amdgcn_s_barrier();                                         \
        __builtin_amdgcn_sched_barrier(0);                                    \
        const bf16_t* Ac = sm + c * 16384;                                    \
        const bf16_t* Bc = Ac + 8192;                                         \
        bf16x8 a8[4][2], b8[4][2];                                            \
        PLOAD();                                                              \
        asm volatile("s_waitcnt lgkmcnt(0)" ::: "memory");                    \
        __builtin_amdgcn_sched_barrier(0);                                    \
        __builtin_amdgcn_s_barrier();                                        \
        __builtin_amdgcn_sched_barrier(0);                                    \
        __builtin_amdgcn_s_setprio(1);                                        \
        PMM();                                                                \
        __builtin_amdgcn_s_setprio(0);                                        \
    }

template <typename TC, int ACCUM, int RELU>
__global__ __launch_bounds__(256, 2) void gemm_pipe(
    const bf16_t* __restrict__ Ag, const bf16_t* __restrict__ Bg, TC* __restrict__ Cg,
    int K, int lda, int ldb, int ldc,
    long long sAz, long long sBz, long long sCz,
    const float* __restrict__ bias)
{
    extern __shared__ __align__(16) bf16_t sm[];
    int z = blockIdx.z;
    Ag += z * sAz; Bg += z * sBz; Cg += z * sCz;

    int tid = threadIdx.x;
    int wave = tid >> 6, lane = tid & 63;
    int wm = wave >> 1, wn = wave & 1;
    int row16 = lane & 15, quad = lane >> 4;
    int m0 = blockIdx.x * 128, n0 = blockIdx.y * 128;

    f32x4 acc[4][4] = {};
    int nt = K >> 6;
    PIPE_BODY(0, nt);

#pragma unroll
    for (int mf = 0; mf < 4; mf++) {
#pragma unroll
        for (int nf = 0; nf < 4; nf++) {
#pragma unroll
            for (int r = 0; r < 4; r++) {
                int m = m0 + wm * 64 + mf * 16 + quad * 4 + r;
                int n = n0 + wn * 64 + nf * 16 + row16;
                float vv = acc[mf][nf][r];
                if (bias) vv += bias[n];
                if (ACCUM) vv += (float)Cg[(long long)m * ldc + n];
                if (RELU) vv = fmaxf(vv, 0.f);
                Cg[(long long)m * ldc + n] = (TC)vv;
            }
        }
    }
}

// Split-K variant: grid.z = SPLIT. z==0 accumulates (+bias) into fp32 C
// (the residual x); z>0 writes fp32 partials P[(z-1)*NX], reduced by the
// downstream reduce_ln_kernel fused into the next LayerNorm.
template <int SPLIT>
__global__ __launch_bounds__(256, 2) void gemm_pipe_splitk(
    const bf16_t* __restrict__ Ag, const bf16_t* __restrict__ Bg,
    float* __restrict__ Cg, float* __restrict__ Pg,
    int K, int lda, int ldb, int ldc, const float* __restrict__ bias)
{
    extern __shared__ __align__(16) bf16_t sm[];
    int z = blockIdx.z;
    int kbeg = z * (K / SPLIT);

    int tid = threadIdx.x;
    int wave = tid >> 6, lane = tid & 63;
    int wm = wave >> 1, wn = wave & 1;
    int row16 = lane & 15, quad = lane >> 4;
    int m0 = blockIdx.x * 128, n0 = blockIdx.y * 128;

    f32x4 acc[4][4] = {};
    int nt = (K / SPLIT) >> 6;
    PIPE_BODY(kbeg, nt);

    const long long NXc = (long long)BB * TT * DD;
#pragma unroll
    for (int mf = 0; mf < 4; mf++) {
#pragma unroll
        for (int nf = 0; nf < 4; nf++) {
#pragma unroll
            for (int r = 0; r < 4; r++) {
                int m = m0 + wm * 64 + mf * 16 + quad * 4 + r;
                int n = n0 + wn * 64 + nf * 16 + row16;
                float vv = acc[mf][nf][r];
                long long ci = (long long)m * ldc + n;
                if (z == 0) {
                    if (bias) vv += bias[n];
                    Cg[ci] = Cg[ci] + vv;
                } else {
                    Pg[(long long)(z - 1) * NXc + ci] = vv;
                }
            }
        }
    }
}

// ---------------------------------------------------------------------------
extern "C" void kernel_launch(void* const* d_in, const int* in_sizes, int n_in,
                              void* d_out, int out_size, void* d_ws, size_t ws_size,
                              hipStream_t stream)
{
    const int*   tokens = (const int*)d_in[0];
    const float* masks  = (const float*)d_in[1];
    const int*   ab     = (const int*)d_in[2];
    const float* embed  = (const float*)d_in[3];
    const float* Wq     = (const float*)d_in[4];
    const float* Wk     = (const float*)d_in[5];
    const float* Wv     = (const float*)d_in[6];
    const float* Wo     = (const float*)d_in[7];
    const float* be     = (const float*)d_in[8];
    const float* bs     = (const float*)d_in[9];
    const float* ln_g   = (const float*)d_in[10];
    const float* ln_b   = (const float*)d_in[11];
    const float* ff1w   = (const float*)d_in[12];
    const float* ff1b   = (const float*)d_in[13];
    const float* ff2w   = (const float*)d_in[14];
    const float* ff2b   = (const float*)d_in[15];
    const float* lng    = (const float*)d_in[16];
    const float* lnb    = (const float*)d_in[17];
    float* out = (float*)d_out;

    const long long NX = (long long)BB * TT * DD;          // 4,194,304 (=B*T*T)
    float* x     = (float*)d_ws;                           // NX f32
    float* ks    = x + NX;                                 // B*T*H f32
    bf16_t* h_bf = (bf16_t*)(ks + (long long)BB * TT * HH);
    unsigned int* cm = (unsigned int*)(h_bf + NX);         // NX u32, PERSISTENT
    bf16_t* q    = (bf16_t*)(cm + NX);
    bf16_t* k    = q + NX;
    bf16_t* v    = k + NX;
    bf16_t* vT   = v + NX;
    bf16_t* wqT  = vT + NX;                                // per-layer weights
    bf16_t* wkT  = wqT + (long long)DD * DD;
    bf16_t* wvT  = wkT + (long long)DD * DD;
    bf16_t* woT  = wvT + (long long)DD * DD;
    bf16_t* ff1T = woT + (long long)DD * DD;               // [F][D]
    bf16_t* ff2T = ff1T + (long long)DD * FFD;             // [D][F]
    bf16_t* ffm  = ff2T + (long long)FFD * DD;             // [B*T, F] bf16

    // split-K partials live in dead attn tensors (each NX f32 = two NX-bf16):
    float* partFF  = (float*)q;    // q..k dead when ff2 runs / ln#1 reduces
    float* partCtx = (float*)v;    // v..vT dead when wo runs / ln#2 reduces

    const size_t LDSP = 65536;     // 64 KB dynamic LDS for gemm_pipe

    embed_pe_kernel<<<dim3(NX / 256), dim3(256), 0, stream>>>(tokens, embed, x);

    // ---- one-time: cm = {bf16(mask) | 4x4-bit edge counts} ----
    hipMemsetAsync(cm, 0, sizeof(unsigned int) * (size_t)NX, stream);
    cnt_scatter_kernel<<<dim3((EE + 255) / 256), dim3(256), 0, stream>>>(ab, cm);
    cm_mask_kernel<<<dim3((int)(NX / 1024)), dim3(256), 0, stream>>>(cm, masks);

    for (int l = 0; l < LNUM; l++) {
        // ln#1: for l>0 also folds in the previous layer's FF2 split-K
        // partial (x += P; h = LN(x)). Runs before qkv overwrites q..k.
        if (l == 0) {
            ln_kernel<bf16_t><<<dim3(BB * TT), dim3(256), 0, stream>>>(
                x, h_bf, ln_g + (l * 2 + 0) * DD, ln_b + (l * 2 + 0) * DD);
        } else {
            reduce_ln_kernel<bf16_t, 1><<<dim3(BB * TT), dim3(256), 0, stream>>>(
                x, partFF, h_bf, ln_g + (l * 2 + 0) * DD, ln_b + (l * 2 + 0) * DD);
        }

        Ptr4 p4;
        p4.p[0] = Wq + (long long)l * DD * HH * AA;
        p4.p[1] = Wk + (long long)l * DD * HH * AA;
        p4.p[2] = Wv + (long long)l * DD * HH * AA;
        p4.p[3] = Wo + (long long)l * HH * AA * DD;
        wconv4_kernel<<<dim3(8, 8, 4), dim3(256), 0, stream>>>(p4, wqT);
        wconv_kernel<<<dim3(FFD / 64, DD / 64, 1), dim3(256), 0, stream>>>(
            ff1w + (long long)l * DD * FFD, ff1T, DD, FFD);
        wconv_kernel<<<dim3(DD / 64, FFD / 64, 1), dim3(256), 0, stream>>>(
            ff2w + (long long)l * FFD * DD, ff2T, FFD, DD);

        const float* ff1b_l = ff1b + (long long)l * FFD;
        const float* ff2b_l = ff2b + (long long)l * DD;

        // q/k/v in ONE launch: 768 blocks, 2 blocks/CU residency
        gemm_pipe<bf16_t, 0, 0><<<dim3(64, 4, 3), dim3(256), LDSP, stream>>>(
            h_bf, wqT, q, 512, 512, 512, 512,
            0LL, (long long)DD * DD, NX, nullptr);

        vtrans_kernel<<<dim3(8, BB * HH), dim3(256), 0, stream>>>(v, vT);
        ksum_kernel<<<dim3(BB * TT * HH / 256), dim3(256), 0, stream>>>(k, ks);

        fused_attn_kernel<<<dim3((TT / 64) * BB * HH), dim3(256), 0, stream>>>(
            q, k, vT, cm, ks,
            be + (long long)l * BIASDIM * AA, bs + (long long)l * AA, h_bf);

        // x += ctx @ Wo  — split-K x2 (512 blocks): z0 accums into x,
        // z1 writes a partial into the (now dead) v..vT region.
        gemm_pipe_splitk<2><<<dim3(64, 4, 2), dim3(256), LDSP, stream>>>(
            h_bf, woT, x, partCtx, 512, 512, 512, 512, nullptr);

        // ln#2 fused with the ctx@Wo partial reduce
        reduce_ln_kernel<bf16_t, 1><<<dim3(BB * TT), dim3(256), 0, stream>>>(
            x, partCtx, h_bf, ln_g + (l * 2 + 1) * DD, ln_b + (l * 2 + 1) * DD);

        // ffm = relu(h @ W1 + b1): 1024 blocks
        gemm_pipe<bf16_t, 0, 1><<<dim3(64, 16, 1), dim3(256), LDSP, stream>>>(
            h_bf, ff1T, ffm, 512, 512, 512, 2048, 0LL, 0LL, 0LL, ff1b_l);

        // x += ffm @ W2 + b2 — split-K x2 (512 blocks): z0 accums into x,
        // z1 writes ONE partial into the (dead) q..k region.
        gemm_pipe_splitk<2><<<dim3(64, 4, 2), dim3(256), LDSP, stream>>>(
            ffm, ff2T, x, partFF, 2048, 2048, 2048, 512, ff2b_l);
    }

    // final LN fused with the last layer's FF2 partial reduce
    reduce_ln_kernel<float, 1><<<dim3(BB * TT), dim3(256), 0, stream>>>(
        x, partFF, out, lng, lnb);
}

// Round 11
// 1473.986 us; speedup vs baseline: 1.0804x; 1.0804x over previous
//
#include <hip/hip_runtime.h>
#include <hip/hip_bf16.h>

#define LNUM 6
#define BB 16
#define TT 512
#define DD 512
#define HH 8
#define AA 64
#define FFD 2048
#define EE 200000
#define BIASDIM 4
#define ATT_NEG (-3.402823466e38f)

typedef __bf16 bf16_t;
typedef __attribute__((ext_vector_type(8))) __bf16 bf16x8;
typedef __attribute__((ext_vector_type(4))) float f32x4;

typedef __attribute__((address_space(3))) void lds_void;
typedef const __attribute__((address_space(1))) void glb_void;

__device__ __forceinline__ void async_load16(const bf16_t* g, bf16_t* l) {
    __builtin_amdgcn_global_load_lds((glb_void*)g, (lds_void*)l, 16, 0, 0);
}

// ---------------------------------------------------------------------------
// Embedding + positional encoding (fp32 out)
// ---------------------------------------------------------------------------
__global__ __launch_bounds__(256) void embed_pe_kernel(
    const int* __restrict__ tokens, const float* __restrict__ embed,
    float* __restrict__ x)
{
    int idx = blockIdx.x * 256 + threadIdx.x;
    int d  = idx & (DD - 1);
    int bt = idx >> 9;
    int t  = bt & (TT - 1);
    int tok = tokens[bt];
    float e = embed[(long long)tok * DD + d] * 22.62741699796952f; // sqrt(512)
    float p = (float)(2 * (d >> 1)) * (1.0f / (float)DD);
    float denom = exp2f(p * 13.287712379549449f);  // 10000^p
    float angle = (float)t / denom;
    float pe = (d & 1) ? cosf(angle) : sinf(angle);
    x[idx] = e + pe;
}

// ---------------------------------------------------------------------------
// LayerNorm over D=512, fp32 in, TO out
// ---------------------------------------------------------------------------
template <typename TO>
__global__ __launch_bounds__(256) void ln_kernel(
    const float* __restrict__ x, TO* __restrict__ y,
    const float* __restrict__ g, const float* __restrict__ b)
{
    long long row = blockIdx.x;
    const float* xr = x + row * DD;
    int tid = threadIdx.x;
    float v0 = xr[tid], v1 = xr[tid + 256];
    float s = v0 + v1, sq = v0 * v0 + v1 * v1;
#pragma unroll
    for (int o = 32; o > 0; o >>= 1) {
        s  += __shfl_down(s, o);
        sq += __shfl_down(sq, o);
    }
    __shared__ float ss[4], sq4[4];
    if ((tid & 63) == 0) { ss[tid >> 6] = s; sq4[tid >> 6] = sq; }
    __syncthreads();
    float st  = ss[0] + ss[1] + ss[2] + ss[3];
    float sqt = sq4[0] + sq4[1] + sq4[2] + sq4[3];
    float mean = st * (1.0f / DD);
    float var  = sqt * (1.0f / DD) - mean * mean;
    float inv  = rsqrtf(var + 1e-3f);
    y[row * DD + tid]       = (TO)((v0 - mean) * inv * g[tid]       + b[tid]);
    y[row * DD + tid + 256] = (TO)((v1 - mean) * inv * g[tid + 256] + b[tid + 256]);
}

// ---------------------------------------------------------------------------
// Fused split-K partial reduce + residual update + LayerNorm.
// ---------------------------------------------------------------------------
template <typename TO, int S>
__global__ __launch_bounds__(256) void reduce_ln_kernel(
    float* __restrict__ x, const float* __restrict__ P,
    TO* __restrict__ y, const float* __restrict__ g, const float* __restrict__ b)
{
    const long long NXc = (long long)BB * TT * DD;
    long long row = blockIdx.x;
    int tid = threadIdx.x;
    long long i0 = row * DD + tid;
    float v0 = x[i0], v1 = x[i0 + 256];
#pragma unroll
    for (int s = 0; s < S; s++) {
        v0 += P[(long long)s * NXc + i0];
        v1 += P[(long long)s * NXc + i0 + 256];
    }
    x[i0] = v0; x[i0 + 256] = v1;
    float s2 = v0 + v1, sq = v0 * v0 + v1 * v1;
#pragma unroll
    for (int o = 32; o > 0; o >>= 1) {
        s2 += __shfl_down(s2, o);
        sq += __shfl_down(sq, o);
    }
    __shared__ float ss[4], sq4[4];
    if ((tid & 63) == 0) { ss[tid >> 6] = s2; sq4[tid >> 6] = sq; }
    __syncthreads();
    float st  = ss[0] + ss[1] + ss[2] + ss[3];
    float sqt = sq4[0] + sq4[1] + sq4[2] + sq4[3];
    float mean = st * (1.0f / DD);
    float var  = sqt * (1.0f / DD) - mean * mean;
    float inv  = rsqrtf(var + 1e-3f);
    y[i0]       = (TO)((v0 - mean) * inv * g[tid]       + b[tid]);
    y[i0 + 256] = (TO)((v1 - mean) * inv * g[tid + 256] + b[tid + 256]);
}

// ---------------------------------------------------------------------------
// ksum[b,t,h] = sum_a k_bf[b,t,h,a]
// ---------------------------------------------------------------------------
__global__ __launch_bounds__(256) void ksum_kernel(
    const bf16_t* __restrict__ k, float* __restrict__ ks)
{
    int idx = blockIdx.x * 256 + threadIdx.x;
    long long base = (long long)idx * AA;
    float s = 0.f;
#pragma unroll
    for (int a = 0; a < AA; a++) s += (float)k[base + a];
    ks[idx] = s;
}

// ---------------------------------------------------------------------------
// ONE-TIME edge-count scatter: cm[b,q,k] += 1 << (4*type).
// ---------------------------------------------------------------------------
__global__ __launch_bounds__(256) void cnt_scatter_kernel(
    const int* __restrict__ ab, unsigned int* __restrict__ cm)
{
    int e = blockIdx.x * 256 + threadIdx.x;
    if (e < EE) {
        int ty = ab[e * 4 + 0];
        int b  = ab[e * 4 + 1];
        int q  = ab[e * 4 + 2];
        int kk = ab[e * 4 + 3];
        atomicAdd(&cm[((long long)b * TT + q) * TT + kk], 1u << (4 * ty));
    }
}

// ONE-TIME: fold bf16(mask) into the hi16 of cm. {bf16(mask) | 4x4-bit cnt}
__global__ __launch_bounds__(256) void cm_mask_kernel(
    unsigned int* __restrict__ cm, const float* __restrict__ masks)
{
    long long i = ((long long)blockIdx.x * 256 + threadIdx.x) * 4;
    uint4 c = *(const uint4*)(cm + i);
    f32x4 m = *(const f32x4*)(masks + i);
    c.x = (__float_as_uint(m[0]) & 0xffff0000u) | (c.x & 0xffffu);
    c.y = (__float_as_uint(m[1]) & 0xffff0000u) | (c.y & 0xffffu);
    c.z = (__float_as_uint(m[2]) & 0xffff0000u) | (c.z & 0xffffu);
    c.w = (__float_as_uint(m[3]) & 0xffff0000u) | (c.w & 0xffffu);
    *(uint4*)(cm + i) = c;
}

// ---------------------------------------------------------------------------
// Weight convert+transpose: in fp32 [R,Cc] -> out bf16 [Cc,R]. 64x64 tiles.
// ---------------------------------------------------------------------------
__global__ __launch_bounds__(256) void wconv_kernel(
    const float* __restrict__ in, bf16_t* __restrict__ out, int R, int Cc)
{
    __shared__ bf16_t tile[64][65];
    int c0 = blockIdx.x * 64, r0 = blockIdx.y * 64;
    int tid = threadIdx.x;
#pragma unroll
    for (int i = 0; i < 16; i++) {
        int idx = tid + i * 256; int r = idx >> 6, c = idx & 63;
        tile[c][r] = (bf16_t)in[(long long)(r0 + r) * Cc + c0 + c];
    }
    __syncthreads();
#pragma unroll
    for (int i = 0; i < 16; i++) {
        int idx = tid + i * 256; int rr = idx >> 6, cc = idx & 63;
        out[(long long)(c0 + rr) * R + r0 + cc] = tile[rr][cc];
    }
}

struct Ptr4 { const float* p[4]; };

__global__ __launch_bounds__(256) void wconv4_kernel(Ptr4 srcs, bf16_t* __restrict__ out)
{
    __shared__ bf16_t tile[64][65];
    int z = blockIdx.z;
    const float* in = srcs.p[z];
    bf16_t* o = out + (long long)z * DD * DD;
    int c0 = blockIdx.x * 64, r0 = blockIdx.y * 64;
    int tid = threadIdx.x;
#pragma unroll
    for (int i = 0; i < 16; i++) {
        int idx = tid + i * 256; int r = idx >> 6, c = idx & 63;
        tile[c][r] = (bf16_t)in[(long long)(r0 + r) * DD + c0 + c];
    }
    __syncthreads();
#pragma unroll
    for (int i = 0; i < 16; i++) {
        int idx = tid + i * 256; int rr = idx >> 6, cc = idx & 63;
        o[(long long)(c0 + rr) * DD + r0 + cc] = tile[rr][cc];
    }
}

// ---------------------------------------------------------------------------
// v [B,T,H,A] bf16 -> vT [B,H,A,T] bf16
// ---------------------------------------------------------------------------
__global__ __launch_bounds__(256) void vtrans_kernel(
    const bf16_t* __restrict__ v, bf16_t* __restrict__ vT)
{
    __shared__ bf16_t tile[64][65];
    int bh = blockIdx.y; int b = bh >> 3, h = bh & 7;
    int t0 = blockIdx.x * 64;
    int tid = threadIdx.x;
#pragma unroll
    for (int i = 0; i < 16; i++) {
        int idx = tid + i * 256; int r = idx >> 6, c = idx & 63;  // r: t, c: a
        tile[c][r] = v[((long long)(b * TT + t0 + r) * HH + h) * AA + c];
    }
    __syncthreads();
#pragma unroll
    for (int i = 0; i < 16; i++) {
        int idx = tid + i * 256; int a = idx >> 6, t2 = idx & 63;
        vT[(((long long)b * HH + h) * AA + a) * TT + t0 + t2] = tile[a][t2];
    }
}

// ---------------------------------------------------------------------------
// Fused attention — EXACT R9 version (best attn measured in cm family).
// ---------------------------------------------------------------------------
__global__ __launch_bounds__(256) void fused_attn_kernel(
    const bf16_t* __restrict__ qg, const bf16_t* __restrict__ kg,
    const bf16_t* __restrict__ vT, const unsigned int* __restrict__ cm,
    const float* __restrict__ ksum, const float* __restrict__ be_l,
    const float* __restrict__ bs_l, bf16_t* __restrict__ ctx)
{
    __shared__ __align__(16) bf16_t Ks[64 * 64];
    __shared__ __align__(16) bf16_t Vs[64 * 64];
    __shared__ __align__(16) bf16_t Plds[4 * 16 * 88];
    __shared__ float evs[BIASDIM];

    int tid = threadIdx.x;
    int wave = tid >> 6, lane = tid & 63;
    int row16 = lane & 15, quad = lane >> 4;
    int bid = blockIdx.x;
    int bh = bid & 127; int b = bh >> 3, h = bh & 7;
    int qw = (bid >> 7) * 64 + wave * 16;

    if (wave == 0) {
        float bsv = bs_l[lane];
#pragma unroll
        for (int t = 0; t < BIASDIM; t++) {
            float p = be_l[t * AA + lane] * bsv;
#pragma unroll
            for (int off = 32; off > 0; off >>= 1) p += __shfl_xor(p, off);
            if (lane == 0) evs[t] = p;
        }
    }

    bf16x8 qf[2];
    {
        const bf16_t* qp = qg + (((long long)b * TT + qw + row16) * HH + h) * AA + quad * 8;
        qf[0] = *(const bf16x8*)(qp);
        qf[1] = *(const bf16x8*)(qp + 32);
    }

    f32x4 o[4] = {};
    float m_r[4], l_r[4];
#pragma unroll
    for (int r = 0; r < 4; r++) { m_r[r] = -3.0e38f; l_r[r] = 0.f; }

    bf16_t* Pw = Plds + wave * 16 * 88;
    const unsigned int* cmbase = cm + (long long)b * TT * TT;
    const float* ksbase = ksum + (long long)b * TT * HH + h;

    for (int kt = 0; kt < 8; kt++) {
        int t0 = kt * 64;

        unsigned int cmw[4][4];
        float ksv4[4];
#pragma unroll
        for (int n = 0; n < 4; n++) {
            int ktok = t0 + n * 16 + row16;
            ksv4[n] = ksbase[(long long)ktok * HH];
#pragma unroll
            for (int r = 0; r < 4; r++)
                cmw[n][r] = cmbase[(long long)(qw + quad * 4 + r) * TT + ktok];
        }

#pragma unroll
        for (int p = tid; p < 512; p += 256) {
            int r = p >> 3, s = p & 7, c = s ^ (r & 7);
            async_load16(kg + (((long long)b * TT + t0 + r) * HH + h) * AA + c * 8,
                         Ks + p * 8);
        }
#pragma unroll
        for (int p = tid; p < 512; p += 256) {
            int r = p >> 3, s = p & 7, c = s ^ (r & 7);
            async_load16(vT + ((long long)bh * AA + r) * TT + t0 + c * 8,
                         Vs + p * 8);
        }
        __syncthreads();

        f32x4 s4[4] = {};
        __builtin_amdgcn_s_setprio(1);
#pragma unroll
        for (int n = 0; n < 4; n++) {
            int row = n * 16 + row16;
            int sw = row & 7;
            bf16x8 kf0 = *(const bf16x8*)(Ks + row * 64 + ((quad ^ sw) * 8));
            bf16x8 kf1 = *(const bf16x8*)(Ks + row * 64 + (((quad + 4) ^ sw) * 8));
            s4[n] = __builtin_amdgcn_mfma_f32_16x16x32_bf16(qf[0], kf0, s4[n], 0, 0, 0);
            s4[n] = __builtin_amdgcn_mfma_f32_16x16x32_bf16(qf[1], kf1, s4[n], 0, 0, 0);
        }
        __builtin_amdgcn_s_setprio(0);

        float e0 = evs[0], e1 = evs[1], e2 = evs[2], e3 = evs[3];
        float val[4][4];
#pragma unroll
        for (int n = 0; n < 4; n++) {
#pragma unroll
            for (int r = 0; r < 4; r++) {
                unsigned int w = cmw[n][r];
                float mk = __uint_as_float(w & 0xffff0000u);
                float d = e0 * (float)(w & 15u)
                        + e1 * (float)((w >> 4) & 15u)
                        + e2 * (float)((w >> 8) & 15u)
                        + e3 * (float)((w >> 12) & 15u);
                float vv = 0.125f * fmaf(d, ksv4[n], s4[n][r]);
                val[n][r] = (mk == 0.f) ? ATT_NEG : vv * mk;
            }
        }

        float scl[4];
#pragma unroll
        for (int r = 0; r < 4; r++) {
            float mx = fmaxf(fmaxf(val[0][r], val[1][r]), fmaxf(val[2][r], val[3][r]));
#pragma unroll
            for (int off = 1; off < 16; off <<= 1) mx = fmaxf(mx, __shfl_xor(mx, off));
            float mnew = fmaxf(m_r[r], mx);
            float sc = __expf(m_r[r] - mnew);
            float ps = 0.f;
#pragma unroll
            for (int n = 0; n < 4; n++) {
                float p = __expf(val[n][r] - mnew);
                val[n][r] = p;
                ps += p;
            }
#pragma unroll
            for (int off = 1; off < 16; off <<= 1) ps += __shfl_xor(ps, off);
            l_r[r] = l_r[r] * sc + ps;
            m_r[r] = mnew;
            scl[r] = sc;
        }
#pragma unroll
        for (int j = 0; j < 4; j++)
#pragma unroll
            for (int r = 0; r < 4; r++) o[j][r] *= scl[r];

#pragma unroll
        for (int n = 0; n < 4; n++)
#pragma unroll
            for (int r = 0; r < 4; r++)
                Pw[(quad * 4 + r) * 88 + n * 16 + row16] = (bf16_t)val[n][r];
        asm volatile("s_waitcnt lgkmcnt(0)" ::: "memory");

        bf16x8 pa0 = *(const bf16x8*)(Pw + row16 * 88 + quad * 8);
        bf16x8 pa1 = *(const bf16x8*)(Pw + row16 * 88 + 32 + quad * 8);
        __builtin_amdgcn_s_setprio(1);
#pragma unroll
        for (int j = 0; j < 4; j++) {
            int row = j * 16 + row16;
            int sw = row & 7;
            bf16x8 vb0 = *(const bf16x8*)(Vs + row * 64 + ((quad ^ sw) * 8));
            bf16x8 vb1 = *(const bf16x8*)(Vs + row * 64 + (((quad + 4) ^ sw) * 8));
            o[j] = __builtin_amdgcn_mfma_f32_16x16x32_bf16(pa0, vb0, o[j], 0, 0, 0);
            o[j] = __builtin_amdgcn_mfma_f32_16x16x32_bf16(pa1, vb1, o[j], 0, 0, 0);
        }
        __builtin_amdgcn_s_setprio(0);
        __syncthreads();
    }

#pragma unroll
    for (int r = 0; r < 4; r++) {
        float invl = 1.0f / l_r[r];
        int qgl = qw + quad * 4 + r;
        bf16_t* cp = ctx + (((long long)b * TT + qgl) * HH + h) * AA;
#pragma unroll
        for (int j = 0; j < 4; j++)
            cp[j * 16 + row16] = (bf16_t)(o[j][r] * invl);
    }
}

// ===========================================================================
// gemm256: 256x256 tile, BK=64, 8 waves (2M x 4N), 128 KB dbuf LDS, m201's
// 8-phase/counted-vmcnt schedule adapted to K-half staging:
//  Staging unit = half K-tile: A[256][32] or B[256][32] bf16 = 16 KB, linear
//  layout [128 lds-rows][8 chunks16B] holding row-pairs (row = 2j + (cl>>2)),
//  8-chunk XOR swizzle cl = cphys ^ (j&7) (proven 0-conflict geometry),
//  pre-swizzled global source + swizzled ds_read (both-sides rule).
//  Per K-tile, 4 phases (ph0 ks0/Mg0, ph1 ks0/Mg1, ph2 ks1/Mg0, ph3 ks1/Mg1):
//   ph0: stage Ak0(t+1); vmcnt(6); s_barrier; 8 ds_read; lgkm0; 16 MFMA
//   ph1: stage Bk0(t+1);                      4 ds_read; lgkm0; 16 MFMA
//   ph2: stage Ak1(t+1); vmcnt(6); s_barrier; 8 ds_read; lgkm0; 16 MFMA
//   ph3: stage Bk1(t+1);                      4 ds_read; lgkm0; 16 MFMA
//  Depth: 3 half-tiles (6 loads) in flight across barriers; 2 barriers +
//  2 counted waits per 64-K (vs old pipe's full-tile depth-1).
//  RAW: vmcnt(6) leaves exactly the 3 newest stages outstanding -> the
//  half-tiles needed this phase (issued >=3 stages ago) are retired (FIFO).
//  Tail iter (no stages): vmcnt(4) at ph0, vmcnt(0) at ph2.
//  WAR: a slot staged at iter t targets buf^1, whose last readers ran at
//  iter t-1 with lgkm(0) drained before their ph2/ph0 barrier; every stage
//  is issued after this wave passed a barrier that all waves' drains
//  precede. QKVC: N=1536 batches wq|wk|wv (contiguous); BN=256 keeps each
//  block inside one 512-col output -> per-block z remap.
// ===========================================================================
#define S256(Gb, ld, rb, kc0, so)                                             \
    _Pragma("unroll")                                                         \
    for (int i5 = 0; i5 < 2; i5++) {                                          \
        int s5 = tid + i5 * 512;                                              \
        int j5 = s5 >> 3, cp5 = s5 & 7, cl5 = cp5 ^ (j5 & 7);                 \
        async_load16((Gb) + (long long)((rb) + 2 * j5 + (cl5 >> 2)) * (ld)    \
                         + (kc0) + (cl5 & 3) * 8,                             \
                     sm + (so) + s5 * 8);                                     \
    }

#define LDA256(bo, ks, mg)                                                    \
    _Pragma("unroll")                                                         \
    for (int mf = 0; mf < 4; mf++) {                                          \
        int ra = wm * 128 + ((mg) * 4 + mf) * 16 + row16;                     \
        int j5 = ra >> 1;                                                     \
        int cl5 = ((ra & 1) * 4 + quad) ^ (j5 & 7);                           \
        a8[mf] = *(const bf16x8*)(sm + (bo) + (ks) * 8192 + j5 * 64 + cl5 * 8);\
    }

#define LDB256(bo, ks)                                                        \
    _Pragma("unroll")                                                         \
    for (int nf = 0; nf < 4; nf++) {                                          \
        int rb2 = wn * 64 + nf * 16 + row16;                                  \
        int j5 = rb2 >> 1;                                                    \
        int cl5 = ((rb2 & 1) * 4 + quad) ^ (j5 & 7);                          \
        b8[nf] = *(const bf16x8*)(sm + (bo) + 16384 + (ks) * 8192             \
                                  + j5 * 64 + cl5 * 8);                       \
    }

#define MM256(mg)                                                             \
    _Pragma("unroll")                                                         \
    for (int mf = 0; mf < 4; mf++)                                            \
        _Pragma("unroll")                                                     \
        for (int nf = 0; nf < 4; nf++)                                        \
            acc[(mg) * 4 + mf][nf] = __builtin_amdgcn_mfma_f32_16x16x32_bf16( \
                a8[mf], b8[nf], acc[(mg) * 4 + mf][nf], 0, 0, 0);

template <typename TC, int RELU, int QKVC>
__global__ __launch_bounds__(512, 2) void gemm256(
    const bf16_t* __restrict__ Ag, const bf16_t* __restrict__ Bg,
    TC* __restrict__ Cg, int K, int lda, int ldb, int ldc,
    long long sCz, const float* __restrict__ bias)
{
    extern __shared__ __align__(16) bf16_t sm[];
    int tid = threadIdx.x;
    int wave = tid >> 6, lane = tid & 63;
    int wm = wave >> 2, wn = wave & 3;
    int row16 = lane & 15, quad = lane >> 4;
    int m0 = blockIdx.x * 256, n0 = blockIdx.y * 256;

    f32x4 acc[8][4] = {};
    int nt = K >> 6;

    // prologue: tile 0 -> buf0 (order Ak0, Bk0, Ak1, Bk1)
    S256(Ag, lda, m0, 0, 0);
    S256(Bg, ldb, n0, 0, 16384);
    S256(Ag, lda, m0, 32, 8192);
    S256(Bg, ldb, n0, 32, 16384 + 8192);

    for (int t = 0; t < nt; ++t) {
        int bo = (t & 1) * 32768;
        int bs = 32768 - bo;
        int kn = (t + 1) * 64;
        bf16x8 a8[4], b8[4];
        // ---- phase 0: ks0, M-group 0 ----
        if (t + 1 < nt) {
            S256(Ag, lda, m0, kn, bs);
            asm volatile("s_waitcnt vmcnt(6)" ::: "memory");
        } else {
            asm volatile("s_waitcnt vmcnt(4)" ::: "memory");
        }
        __builtin_amdgcn_sched_barrier(0);
        __builtin_amdgcn_s_barrier();
        __builtin_amdgcn_sched_barrier(0);
        LDA256(bo, 0, 0); LDB256(bo, 0);
        asm volatile("s_waitcnt lgkmcnt(0)" ::: "memory");
        __builtin_amdgcn_sched_barrier(0);
        __builtin_amdgcn_s_setprio(1); MM256(0); __builtin_amdgcn_s_setprio(0);
        // ---- phase 1: ks0, M-group 1 ----
        if (t + 1 < nt) S256(Bg, ldb, n0, kn, bs + 16384);
        LDA256(bo, 0, 1);
        asm volatile("s_waitcnt lgkmcnt(0)" ::: "memory");
        __builtin_amdgcn_sched_barrier(0);
        __builtin_amdgcn_s_setprio(1); MM256(1); __builtin_amdgcn_s_setprio(0);
        // ---- phase 2: ks1, M-group 0 ----
        if (t + 1 < nt) {
            S256(Ag, lda, m0, kn + 32, bs + 8192);
            asm volatile("s_waitcnt vmcnt(6)" ::: "memory");
        } else {
            asm volatile("s_waitcnt vmcnt(0)" ::: "memory");
        }
        __builtin_amdgcn_sched_barrier(0);
        __builtin_amdgcn_s_barrier();
        __builtin_amdgcn_sched_barrier(0);
        LDA256(bo, 1, 0); LDB256(bo, 1);
        asm volatile("s_waitcnt lgkmcnt(0)" ::: "memory");
        __builtin_amdgcn_sched_barrier(0);
        __builtin_amdgcn_s_setprio(1); MM256(0); __builtin_amdgcn_s_setprio(0);
        // ---- phase 3: ks1, M-group 1 ----
        if (t + 1 < nt) S256(Bg, ldb, n0, kn + 32, bs + 16384 + 8192);
        LDA256(bo, 1, 1);
        asm volatile("s_waitcnt lgkmcnt(0)" ::: "memory");
        __builtin_amdgcn_sched_barrier(0);
        __builtin_amdgcn_s_setprio(1); MM256(1); __builtin_amdgcn_s_setprio(0);
    }

    // epilogue
#pragma unroll
    for (int mf2 = 0; mf2 < 8; mf2++) {
#pragma unroll
        for (int nf2 = 0; nf2 < 4; nf2++) {
#pragma unroll
            for (int r = 0; r < 4; r++) {
                int m  = m0 + wm * 128 + mf2 * 16 + quad * 4 + r;
                int ng = n0 + wn * 64 + nf2 * 16 + row16;
                float vv = acc[mf2][nf2][r];
                if (bias) vv += bias[ng];
                if (RELU) vv = fmaxf(vv, 0.f);
                if (QKVC) {
                    TC* Cb = Cg + (long long)(ng >> 9) * sCz;
                    Cb[(long long)m * ldc + (ng & 511)] = (TC)vv;
                } else {
                    Cg[(long long)m * ldc + ng] = (TC)vv;
                }
            }
        }
    }
}

// ===========================================================================
// gemm_pipe (exact R4 version): 128x128, BK=64, 4 waves, 64 KB dbuf LDS,
// counted-vmcnt pipeline. Kept for ff2/wo (N=512 split-K shapes).
// ===========================================================================
#define PSTAGE(kc0, slot)                                                     \
    {                                                                         \
        bf16_t* At = sm + (slot) * 16384;                                     \
        bf16_t* Bt = At + 8192;                                               \
        _Pragma("unroll")                                                     \
        for (int i = 0; i < 4; i++) {                                         \
            int qq = tid + i * 256;                                           \
            int r = qq >> 3, ck = qq & 7;                                     \
            int cc = (kc0) + ((ck ^ (r & 7)) * 8);                            \
            async_load16(Ag + (long long)(m0 + r) * lda + cc, At + qq * 8);   \
            async_load16(Bg + (long long)(n0 + r) * ldb + cc, Bt + qq * 8);   \
        }                                                                     \
    }

#define PLOAD()                                                               \
    _Pragma("unroll")                                                         \
    for (int mf = 0; mf < 4; mf++) {                                          \
        int ra = wm * 64 + mf * 16 + row16;                                   \
        _Pragma("unroll")                                                     \
        for (int ks2 = 0; ks2 < 2; ks2++)                                     \
            a8[mf][ks2] = *(const bf16x8*)(Ac + ra * 64 +                     \
                              (((ks2 * 4 + quad) ^ (ra & 7)) * 8));           \
    }                                                                         \
    _Pragma("unroll")                                                         \
    for (int nf = 0; nf < 4; nf++) {                                          \
        int rb = wn * 64 + nf * 16 + row16;                                   \
        _Pragma("unroll")                                                     \
        for (int ks2 = 0; ks2 < 2; ks2++)                                     \
            b8[nf][ks2] = *(const bf16x8*)(Bc + rb * 64 +                     \
                              (((ks2 * 4 + quad) ^ (rb & 7)) * 8));           \
    }

#define PMM()                                                                 \
    _Pragma("unroll")                                                         \
    for (int mf = 0; mf < 4; mf++)                                            \
        _Pragma("unroll")                                                     \
        for (int nf = 0; nf < 4; nf++)                                        \
            _Pragma("unroll")                                                 \
            for (int ks2 = 0; ks2 < 2; ks2++)                                 \
                acc[mf][nf] = __builtin_amdgcn_mfma_f32_16x16x32_bf16(        \
                    a8[mf][ks2], b8[nf][ks2], acc[mf][nf], 0, 0, 0);

#define PIPE_BODY(KBEG, NT)                                                   \
    PSTAGE((KBEG), 0);                                                        \
    int c = 0;                                                                \
    for (int t = 0; t < (NT); ++t, c ^= 1) {                                  \
        if (t + 1 < (NT)) {                                                   \
            PSTAGE((KBEG) + (t + 1) * 64, c ^ 1);                             \
            asm volatile("s_waitcnt vmcnt(8)" ::: "memory");                  \
        } else {                                                              \
            asm volatile("s_waitcnt vmcnt(0)" ::: "memory");                  \
        }                                                                     \
        __builtin_amdgcn_sched_barrier(0);                                    \
        __builtin_amdgcn_s_barrier();                                         \
        __builtin_amdgcn_sched_barrier(0);                                    \
        const bf16_t* Ac = sm + c * 16384;                                    \
        const bf16_t* Bc = Ac + 8192;                                         \
        bf16x8 a8[4][2], b8[4][2];                                            \
        PLOAD();                                                              \
        asm volatile("s_waitcnt lgkmcnt(0)" ::: "memory");                    \
        __builtin_amdgcn_sched_barrier(0);                                    \
        __builtin_amdgcn_s_barrier();                                        \
        __builtin_amdgcn_sched_barrier(0);                                    \
        __builtin_amdgcn_s_setprio(1);                                        \
        PMM();                                                                \
        __builtin_amdgcn_s_setprio(0);                                        \
    }

// Split-K variant: z==0 accumulates (+bias) into fp32 C (the residual x);
// z>0 writes fp32 partials, reduced by the fused reduce_ln downstream.
template <int SPLIT>
__global__ __launch_bounds__(256, 2) void gemm_pipe_splitk(
    const bf16_t* __restrict__ Ag, const bf16_t* __restrict__ Bg,
    float* __restrict__ Cg, float* __restrict__ Pg,
    int K, int lda, int ldb, int ldc, const float* __restrict__ bias)
{
    extern __shared__ __align__(16) bf16_t sm[];
    int z = blockIdx.z;
    int kbeg = z * (K / SPLIT);

    int tid = threadIdx.x;
    int wave = tid >> 6, lane = tid & 63;
    int wm = wave >> 1, wn = wave & 1;
    int row16 = lane & 15, quad = lane >> 4;
    int m0 = blockIdx.x * 128, n0 = blockIdx.y * 128;

    f32x4 acc[4][4] = {};
    int nt = (K / SPLIT) >> 6;
    PIPE_BODY(kbeg, nt);

    const long long NXc = (long long)BB * TT * DD;
#pragma unroll
    for (int mf = 0; mf < 4; mf++) {
#pragma unroll
        for (int nf = 0; nf < 4; nf++) {
#pragma unroll
            for (int r = 0; r < 4; r++) {
                int m = m0 + wm * 64 + mf * 16 + quad * 4 + r;
                int n = n0 + wn * 64 + nf * 16 + row16;
                float vv = acc[mf][nf][r];
                long long ci = (long long)m * ldc + n;
                if (z == 0) {
                    if (bias) vv += bias[n];
                    Cg[ci] = Cg[ci] + vv;
                } else {
                    Pg[(long long)(z - 1) * NXc + ci] = vv;
                }
            }
        }
    }
}

// ---------------------------------------------------------------------------
extern "C" void kernel_launch(void* const* d_in, const int* in_sizes, int n_in,
                              void* d_out, int out_size, void* d_ws, size_t ws_size,
                              hipStream_t stream)
{
    const int*   tokens = (const int*)d_in[0];
    const float* masks  = (const float*)d_in[1];
    const int*   ab     = (const int*)d_in[2];
    const float* embed  = (const float*)d_in[3];
    const float* Wq     = (const float*)d_in[4];
    const float* Wk     = (const float*)d_in[5];
    const float* Wv     = (const float*)d_in[6];
    const float* Wo     = (const float*)d_in[7];
    const float* be     = (const float*)d_in[8];
    const float* bs     = (const float*)d_in[9];
    const float* ln_g   = (const float*)d_in[10];
    const float* ln_b   = (const float*)d_in[11];
    const float* ff1w   = (const float*)d_in[12];
    const float* ff1b   = (const float*)d_in[13];
    const float* ff2w   = (const float*)d_in[14];
    const float* ff2b   = (const float*)d_in[15];
    const float* lng    = (const float*)d_in[16];
    const float* lnb    = (const float*)d_in[17];
    float* out = (float*)d_out;

    const long long NX = (long long)BB * TT * DD;          // 4,194,304 (=B*T*T)
    float* x     = (float*)d_ws;                           // NX f32
    float* ks    = x + NX;                                 // B*T*H f32
    bf16_t* h_bf = (bf16_t*)(ks + (long long)BB * TT * HH);
    unsigned int* cm = (unsigned int*)(h_bf + NX);         // NX u32, PERSISTENT
    bf16_t* q    = (bf16_t*)(cm + NX);
    bf16_t* k    = q + NX;
    bf16_t* v    = k + NX;
    bf16_t* vT   = v + NX;
    bf16_t* wqT  = vT + NX;                                // per-layer weights
    bf16_t* wkT  = wqT + (long long)DD * DD;
    bf16_t* wvT  = wkT + (long long)DD * DD;
    bf16_t* woT  = wvT + (long long)DD * DD;
    bf16_t* ff1T = woT + (long long)DD * DD;               // [F][D]
    bf16_t* ff2T = ff1T + (long long)DD * FFD;             // [D][F]
    bf16_t* ffm  = ff2T + (long long)FFD * DD;             // [B*T, F] bf16

    // split-K partials live in dead attn tensors (each NX f32 = two NX-bf16):
    float* partFF  = (float*)q;    // q..k dead when ff2 runs / ln#1 reduces
    float* partCtx = (float*)v;    // v..vT dead when wo runs / ln#2 reduces

    const size_t LDSP = 65536;     // 64 KB  (gemm_pipe)
    const size_t LDS8 = 131072;    // 128 KB (gemm256)

    embed_pe_kernel<<<dim3(NX / 256), dim3(256), 0, stream>>>(tokens, embed, x);

    // ---- one-time: cm = {bf16(mask) | 4x4-bit edge counts} ----
    hipMemsetAsync(cm, 0, sizeof(unsigned int) * (size_t)NX, stream);
    cnt_scatter_kernel<<<dim3((EE + 255) / 256), dim3(256), 0, stream>>>(ab, cm);
    cm_mask_kernel<<<dim3((int)(NX / 1024)), dim3(256), 0, stream>>>(cm, masks);

    for (int l = 0; l < LNUM; l++) {
        if (l == 0) {
            ln_kernel<bf16_t><<<dim3(BB * TT), dim3(256), 0, stream>>>(
                x, h_bf, ln_g + (l * 2 + 0) * DD, ln_b + (l * 2 + 0) * DD);
        } else {
            reduce_ln_kernel<bf16_t, 1><<<dim3(BB * TT), dim3(256), 0, stream>>>(
                x, partFF, h_bf, ln_g + (l * 2 + 0) * DD, ln_b + (l * 2 + 0) * DD);
        }

        Ptr4 p4;
        p4.p[0] = Wq + (long long)l * DD * HH * AA;
        p4.p[1] = Wk + (long long)l * DD * HH * AA;
        p4.p[2] = Wv + (long long)l * DD * HH * AA;
        p4.p[3] = Wo + (long long)l * HH * AA * DD;
        wconv4_kernel<<<dim3(8, 8, 4), dim3(256), 0, stream>>>(p4, wqT);
        wconv_kernel<<<dim3(FFD / 64, DD / 64, 1), dim3(256), 0, stream>>>(
            ff1w + (long long)l * DD * FFD, ff1T, DD, FFD);
        wconv_kernel<<<dim3(DD / 64, FFD / 64, 1), dim3(256), 0, stream>>>(
            ff2w + (long long)l * FFD * DD, ff2T, FFD, DD);

        const float* ff1b_l = ff1b + (long long)l * FFD;
        const float* ff2b_l = ff2b + (long long)l * DD;

        // q/k/v as ONE batched 8192x1536x512 gemm256 (192 blocks of 8 waves)
        gemm256<bf16_t, 0, 1><<<dim3(32, 6), dim3(512), LDS8, stream>>>(
            h_bf, wqT, q, 512, 512, 512, 512, NX, nullptr);

        vtrans_kernel<<<dim3(8, BB * HH), dim3(256), 0, stream>>>(v, vT);
        ksum_kernel<<<dim3(BB * TT * HH / 256), dim3(256), 0, stream>>>(k, ks);

        fused_attn_kernel<<<dim3((TT / 64) * BB * HH), dim3(256), 0, stream>>>(
            q, k, vT, cm, ks,
            be + (long long)l * BIASDIM * AA, bs + (long long)l * AA, h_bf);

        // x += ctx @ Wo  — split-K x2 (512 blocks): z0 accums into x,
        // z1 writes a partial into the (now dead) v..vT region.
        gemm_pipe_splitk<2><<<dim3(64, 4, 2), dim3(256), LDSP, stream>>>(
            h_bf, woT, x, partCtx, 512, 512, 512, 512, nullptr);

        // ln#2 fused with the ctx@Wo partial reduce
        reduce_ln_kernel<bf16_t, 1><<<dim3(BB * TT), dim3(256), 0, stream>>>(
            x, partCtx, h_bf, ln_g + (l * 2 + 1) * DD, ln_b + (l * 2 + 1) * DD);

        // ffm = relu(h @ W1 + b1): 8192x2048x512 gemm256 (256 blocks = 1/CU)
        gemm256<bf16_t, 1, 0><<<dim3(32, 8), dim3(512), LDS8, stream>>>(
            h_bf, ff1T, ffm, 512, 512, 512, 2048, 0LL, ff1b_l);

        // x += ffm @ W2 + b2 — split-K x2 (512 blocks): z0 accums into x,
        // z1 writes ONE partial into the (dead) q..k region.
        gemm_pipe_splitk<2><<<dim3(64, 4, 2), dim3(256), LDSP, stream>>>(
            ffm, ff2T, x, partFF, 2048, 2048, 2048, 512, ff2b_l);
    }

    // final LN fused with the last layer's FF2 partial reduce
    reduce_ln_kernel<float, 1><<<dim3(BB * TT), dim3(256), 0, stream>>>(
        x, partFF, out, lng, lnb);
}